// Round 17
// baseline (575.573 us; speedup 1.0000x reference)
//
#include <hip/hip_runtime.h>
#include <hip/hip_bf16.h>

// GroupedLinear: out[s_e:e_e] = x[s_e:e_e] @ W[e]^T
// T=16384, K=2048, N=5632, E=8. fp32 in/out, bf16 MFMA compute.
// R10 structure (256x128 tile, 8 waves of 64x64, BK=32 triple-buffered
// 72 KiB LDS -> 2 blocks/CU, counted VMCNT(3), 1 barrier/iter) + R12's
// 2D XCD ownership mapping. R10's 516us was pure HBM-wall (2.05 GB @
// 4 TB/s); 2D-XCD cuts fetch ~5x, giving the 2-block MFMA||LDS overlap
// its first fair test.

#define T_TOK 16384
#define K_IN  2048
#define N_OUT 5632
#define NEXP  8

typedef __attribute__((ext_vector_type(8))) short short8;
typedef __attribute__((ext_vector_type(4))) float f32x4;
typedef unsigned short ushort_t;

__device__ __forceinline__ ushort_t f2bf(float x) {
  __hip_bfloat16 h = __float2bfloat16(x);  // RNE
  return *reinterpret_cast<ushort_t*>(&h);
}

// ---------------- fused fp32 -> bf16 conversion prepass ----------------
__global__ void __launch_bounds__(256) cvt2(const float* __restrict__ x,
                                            const float* __restrict__ w,
                                            ushort_t* __restrict__ ox,
                                            ushort_t* __restrict__ ow,
                                            int n8x, int n8t) {
  int i = blockIdx.x * blockDim.x + threadIdx.x;
  int stride = gridDim.x * blockDim.x;
  for (; i < n8t; i += stride) {
    const float* src;
    ushort_t* dst;
    int j;
    if (i < n8x) { src = x; dst = ox; j = i; }
    else         { src = w; dst = ow; j = i - n8x; }
    const float4* p = (const float4*)src + (size_t)j * 2;
    float4 a = p[0], b = p[1];
    short8 v;
    v[0] = (short)f2bf(a.x); v[1] = (short)f2bf(a.y);
    v[2] = (short)f2bf(a.z); v[3] = (short)f2bf(a.w);
    v[4] = (short)f2bf(b.x); v[5] = (short)f2bf(b.y);
    v[6] = (short)f2bf(b.z); v[7] = (short)f2bf(b.w);
    *((short8*)dst + j) = v;
  }
}

// ---------------- 256x128, 2-blocks/CU triple-buffered GEMM ----------------
#define MT3 64              // 16384/256
#define NT3 44              // 5632/128
#define GRID3 (MT3 * NT3)   // 2816 = 8 XCD x 352

#define BAR() do { asm volatile("" ::: "memory"); \
                   __builtin_amdgcn_s_barrier(); \
                   asm volatile("" ::: "memory"); } while (0)
#define VMCNT(n) asm volatile("s_waitcnt vmcnt(" #n ")" ::: "memory")
#define LDF(p, imm) (*(const short8*)((p) + (imm)))

__global__ void __launch_bounds__(512, 4) gemm3(
    const ushort_t* __restrict__ abf, const ushort_t* __restrict__ wbf,
    const int* __restrict__ offs, float* __restrict__ out) {
  // buf = A[256][32] (16 KB) + B[128][32] (8 KB) = 24576 B; 3 bufs = 72 KiB
  __shared__ __align__(16) ushort_t lds[3][12288];

  // 2D XCD ownership: xcd = bid&7 owns tm band [8*xcd, 8*xcd+8);
  // tn outer (loc>>3), tm inner (loc&7) -> W panel shared across band,
  // A band 8 MB fetched from HBM once per XCD.
  int bid = blockIdx.x;
  int loc = bid >> 3;                 // 0..351
  int tn = loc >> 3;                  // 0..43
  int tm = (bid & 7) * 8 + (loc & 7); // 0..63

  const int t = threadIdx.x;
  const int w = t >> 6;   // wave 0..7
  const int l = t & 63;
  const int wm = w >> 1;  // 0..3 : M-quarter (64 rows)
  const int wn = w & 1;   // 0..1 : N-half (64 cols)

  const int row0 = tm * 256;
  int e = 0;
#pragma unroll
  for (int i = 1; i < NEXP; ++i) e += (row0 >= offs[i]) ? 1 : 0;

  const ushort_t* aB = abf + (size_t)row0 * K_IN;
  const ushort_t* wB =
      wbf + (size_t)e * N_OUT * K_IN + (size_t)(tn * 128) * K_IN;

  // ---- stage addressing ----
  // A tile 256x32 = 1024 16B-chunks: thread t covers chunks t and t+512.
  // B tile 128x32 = 512 chunks: thread t covers chunk t.
  // chunk c: row = c>>2, slot = c&3; source col8 = slot ^ ((row>>1)&3)
  // (inverse of the read swizzle). For c=t: row = w*16 + (l>>2),
  // (row>>1)&3 = (l>>3)&3; c+512 adds 128 rows (swz invariant).
  const int srow = w * 16 + (l >> 2);
  const int scol8 = (l & 3) ^ ((l >> 3) & 3);
  const ushort_t* const sA = aB + (size_t)srow * K_IN + scol8 * 8;
  const ushort_t* const sA2 = sA + (size_t)128 * K_IN;
  const ushort_t* const sB = wB + (size_t)srow * K_IN + scol8 * 8;
  const int dbase = w * 512;  // wave-uniform ushort offset (chunk w*64)

  auto stage3 = [&](ushort_t* buf, size_t ko) {
    __builtin_amdgcn_global_load_lds(
        (const __attribute__((address_space(1))) void*)(sA + ko),
        (__attribute__((address_space(3))) void*)(buf + dbase), 16, 0, 0);
    __builtin_amdgcn_global_load_lds(
        (const __attribute__((address_space(1))) void*)(sA2 + ko),
        (__attribute__((address_space(3))) void*)(buf + 4096 + dbase), 16, 0, 0);
    __builtin_amdgcn_global_load_lds(
        (const __attribute__((address_space(1))) void*)(sB + ko),
        (__attribute__((address_space(3))) void*)(buf + 8192 + dbase), 16, 0, 0);
  };

  f32x4 acc[4][4];
#pragma unroll
  for (int i = 0; i < 4; ++i)
#pragma unroll
    for (int j = 0; j < 4; ++j)
#pragma unroll
      for (int r = 0; r < 4; ++r) acc[i][j][r] = 0.f;

  // ---- fragment read bases (swizzled [R][32] layout) ----
  // byte = row*64 + (kgo2 ^ ((row>>1)&3)<<4); row = {wm|wn}*64 + m*16 + l15
  // -> (row>>1)&3 = (l15>>1)&3 (64,16 contribute 0 mod 4 after >>1).
  const int l15 = l & 15;
  const int kgo2 = (l >> 4) * 16;
  const int swzf = ((l15 >> 1) & 3) << 4;
  const int fbase = l15 * 64 + (kgo2 ^ swzf);
  const char* aP[3];
  const char* bP[3];
#pragma unroll
  for (int b = 0; b < 3; ++b) {
    aP[b] = (const char*)&lds[b][0] + wm * 4096 + fbase;
    bP[b] = (const char*)&lds[b][0] + 16384 + wn * 4096 + fbase;
  }

  auto body = [&](const char* aPb, const char* bPb, ushort_t* stgBuf,
                  size_t ko, int wait) {
    if (stgBuf) stage3(stgBuf, ko);
    short8 aF[4], bF[4];
#pragma unroll
    for (int m = 0; m < 4; ++m) aF[m] = LDF(aPb, m * 1024);
#pragma unroll
    for (int n = 0; n < 4; ++n) bF[n] = LDF(bPb, n * 1024);
    __builtin_amdgcn_s_setprio(1);
#pragma unroll
    for (int m = 0; m < 4; ++m)
#pragma unroll
      for (int n = 0; n < 4; ++n)
        acc[m][n] = __builtin_amdgcn_mfma_f32_16x16x32_bf16(aF[m], bF[n],
                                                            acc[m][n], 0, 0, 0);
    __builtin_amdgcn_s_setprio(0);
    if (wait == 3) { VMCNT(3); } else { VMCNT(0); }
    BAR();
  };

  // ---- prologue: kt0 -> buf0, kt1 -> buf1 ----
  stage3(&lds[0][0], 0);
  stage3(&lds[1][0], 32);
  VMCNT(3);  // kt0 landed; kt1's 3 in flight
  BAR();

  // ---- main loop: 64 K-tiles; iter i reads buf[i%3], stages kt i+2 ----
#pragma unroll 1
  for (int g = 0; g < 20; ++g) {
    const int i0 = 3 * g;
    body(aP[0], bP[0], &lds[2][0], (size_t)(i0 + 2) * 32, 3);
    body(aP[1], bP[1], &lds[0][0], (size_t)(i0 + 3) * 32, 3);
    body(aP[2], bP[2], &lds[1][0], (size_t)(i0 + 4) * 32, 3);
  }
  // i = 60, 61: last stages (kt 62 -> buf2, kt 63 -> buf0)
  body(aP[0], bP[0], &lds[2][0], (size_t)62 * 32, 3);
  body(aP[1], bP[1], &lds[0][0], (size_t)63 * 32, 3);
  // i = 62: no stage; drain so kt63 (buf0) is landed
  body(aP[2], bP[2], nullptr, 0, 0);
  // i = 63: final
  body(aP[0], bP[0], nullptr, 0, 0);

  // ---- epilogue: C/D layout col=lane&15, row=(lane>>4)*4+reg ----
  const int cr = (l >> 4) * 4;
  const int cc = l & 15;
  float* ob = out + (size_t)(row0 + wm * 64) * N_OUT + tn * 128 + wn * 64;
#pragma unroll
  for (int m = 0; m < 4; ++m)
#pragma unroll
    for (int n = 0; n < 4; ++n)
#pragma unroll
      for (int r = 0; r < 4; ++r)
        ob[(size_t)(m * 16 + cr + r) * N_OUT + n * 16 + cc] = acc[m][n][r];
}

// ---------------- fallback (ws too small): fp32 reg-staging 128x128 ----------------
#define BM 128
#define BN 128
#define BK 64
#define MT (T_TOK / BM)
#define NTILE (N_OUT / BN)

__global__ void __launch_bounds__(256) gemm_fb(const float* __restrict__ af,
                                               const float* __restrict__ wf,
                                               const int* __restrict__ offs,
                                               float* __restrict__ out) {
  __shared__ __align__(16) ushort_t lsA[BM * BK];
  __shared__ __align__(16) ushort_t lsB[BN * BK];
  int bid = blockIdx.x;
  int wg = (bid & 7) * ((MT * NTILE) >> 3) + (bid >> 3);
  int tm = wg / NTILE, tn = wg - tm * NTILE;
  const int t = threadIdx.x, w = t >> 6, l = t & 63;
  const int row0 = tm * BM;
  int e = 0;
#pragma unroll
  for (int i = 1; i < NEXP; ++i) e += (row0 >= offs[i]) ? 1 : 0;
  const size_t wbase = (size_t)e * ((size_t)N_OUT * K_IN);
  f32x4 acc[4][4];
#pragma unroll
  for (int i = 0; i < 4; ++i)
#pragma unroll
    for (int j = 0; j < 4; ++j)
#pragma unroll
      for (int r = 0; r < 4; ++r) acc[i][j][r] = 0.f;
  const int wm = w >> 1, wn = w & 1;
  const int rA = wm * 64 + (l & 15), rB = wn * 64 + (l & 15);
  const int kgo = (l >> 4) * 8;
  for (int kt = 0; kt < K_IN / BK; ++kt) {
    const int k0 = kt * BK;
    if (kt) __syncthreads();
#pragma unroll
    for (int p = 0; p < 4; ++p) {
      const int ia = (p * 4 + w) * 64 + l;
      const float4* g = (const float4*)(af + (size_t)(row0 + (ia >> 3)) * K_IN +
                                        k0 + (ia & 7) * 8);
      float4 a = g[0], b = g[1];
      short8 v;
      v[0] = (short)f2bf(a.x); v[1] = (short)f2bf(a.y);
      v[2] = (short)f2bf(a.z); v[3] = (short)f2bf(a.w);
      v[4] = (short)f2bf(b.x); v[5] = (short)f2bf(b.y);
      v[6] = (short)f2bf(b.z); v[7] = (short)f2bf(b.w);
      *(short8*)&lsA[ia * 8] = v;
    }
#pragma unroll
    for (int p = 0; p < 4; ++p) {
      const int ib = (p * 4 + w) * 64 + l;
      const float4* g = (const float4*)(wf + wbase +
                                        (size_t)(tn * BN + (ib >> 3)) * K_IN +
                                        k0 + (ib & 7) * 8);
      float4 a = g[0], b = g[1];
      short8 v;
      v[0] = (short)f2bf(a.x); v[1] = (short)f2bf(a.y);
      v[2] = (short)f2bf(a.z); v[3] = (short)f2bf(a.w);
      v[4] = (short)f2bf(b.x); v[5] = (short)f2bf(b.y);
      v[6] = (short)f2bf(b.z); v[7] = (short)f2bf(b.w);
      *(short8*)&lsB[ib * 8] = v;
    }
    __syncthreads();
#pragma unroll
    for (int s = 0; s < 2; ++s) {
      const int ko = s * 32 + kgo;
      short8 aF[4], bFf[4];
#pragma unroll
      for (int i = 0; i < 4; ++i) aF[i] = *(const short8*)&lsA[(rA + i * 16) * BK + ko];
#pragma unroll
      for (int j = 0; j < 4; ++j) bFf[j] = *(const short8*)&lsB[(rB + j * 16) * BK + ko];
#pragma unroll
      for (int i = 0; i < 4; ++i)
#pragma unroll
        for (int j = 0; j < 4; ++j)
          acc[i][j] = __builtin_amdgcn_mfma_f32_16x16x32_bf16(aF[i], bFf[j],
                                                              acc[i][j], 0, 0, 0);
    }
  }
  const int cr = (l >> 4) * 4, cc = l & 15;
  float* ob = out + (size_t)(row0 + wm * 64) * N_OUT + tn * BN + wn * 64;
#pragma unroll
  for (int i = 0; i < 4; ++i)
#pragma unroll
    for (int j = 0; j < 4; ++j)
#pragma unroll
      for (int r = 0; r < 4; ++r)
        ob[(size_t)(i * 16 + cr + r) * N_OUT + j * 16 + cc] = acc[i][j][r];
}

extern "C" void kernel_launch(void* const* d_in, const int* in_sizes, int n_in,
                              void* d_out, int out_size, void* d_ws, size_t ws_size,
                              hipStream_t stream) {
  const float* x = (const float*)d_in[0];
  const float* wt = (const float*)d_in[1];
  const int* offs = (const int*)d_in[2];
  float* out = (float*)d_out;

  const size_t nA = (size_t)T_TOK * K_IN;
  const size_t nW = (size_t)NEXP * N_OUT * K_IN;
  const size_t need = (nA + nW) * sizeof(ushort_t);

  if (ws_size >= need) {
    ushort_t* abf = (ushort_t*)d_ws;
    ushort_t* wbf = abf + nA;
    cvt2<<<2048, 256, 0, stream>>>(x, wt, abf, wbf, (int)(nA / 8),
                                   (int)((nA + nW) / 8));
    gemm3<<<GRID3, 512, 0, stream>>>(abf, wbf, offs, out);
  } else {
    gemm_fb<<<MT * NTILE, 256, 0, stream>>>(x, wt, offs, out);
  }
}

// Round 18
// 476.342 us; speedup vs baseline: 1.2083x; 1.2083x over previous
//
#include <hip/hip_runtime.h>
#include <hip/hip_bf16.h>

// GroupedLinear: out[s_e:e_e] = x[s_e:e_e] @ W[e]^T
// T=16384, K=2048, N=5632, E=8. fp32 in/out, bf16 MFMA compute.
// FINAL = R12 (best measured, reproduced: 477.7-478.0 us total; gemm 354 us,
// FETCH 344 MB, conflicts 0): 256x256 8-phase, 16x16x32 MFMA, T2 swizzle,
// SGB, counted vmcnt, 2D XCD ownership (8-tm band/XCD, tn outer/tm inner).
// Falsified: scheduling beyond SGB (R3-R6), 128^2 (R8), 256x128 (R10/R17),
// TLP/2-block (R10/R17), NT hints (R11), fusion (R13), 32x32 MFMA (R14/15).

#define T_TOK 16384
#define K_IN  2048
#define N_OUT 5632
#define NEXP  8

typedef __attribute__((ext_vector_type(8))) short short8;
typedef __attribute__((ext_vector_type(4))) float f32x4;
typedef unsigned short ushort_t;

__device__ __forceinline__ ushort_t f2bf(float x) {
  __hip_bfloat16 h = __float2bfloat16(x);  // RNE
  return *reinterpret_cast<ushort_t*>(&h);
}

// ---------------- fused fp32 -> bf16 conversion prepass ----------------
__global__ void __launch_bounds__(256) cvt2(const float* __restrict__ x,
                                            const float* __restrict__ w,
                                            ushort_t* __restrict__ ox,
                                            ushort_t* __restrict__ ow,
                                            int n8x, int n8t) {
  int i = blockIdx.x * blockDim.x + threadIdx.x;
  int stride = gridDim.x * blockDim.x;
  for (; i < n8t; i += stride) {
    const float* src;
    ushort_t* dst;
    int j;
    if (i < n8x) { src = x; dst = ox; j = i; }
    else         { src = w; dst = ow; j = i - n8x; }
    const float4* p = (const float4*)src + (size_t)j * 2;
    float4 a = p[0], b = p[1];
    short8 v;
    v[0] = (short)f2bf(a.x); v[1] = (short)f2bf(a.y);
    v[2] = (short)f2bf(a.z); v[3] = (short)f2bf(a.w);
    v[4] = (short)f2bf(b.x); v[5] = (short)f2bf(b.y);
    v[6] = (short)f2bf(b.z); v[7] = (short)f2bf(b.w);
    *((short8*)dst + j) = v;
  }
}

// ---------------- 256x256 8-phase GEMM ----------------
#define MT2 64             // 16384/256
#define NT2 22             // 5632/256
#define GRID2 (MT2 * NT2)  // 1408 = 8 XCD x 176

#define BAR() do { asm volatile("" ::: "memory"); \
                   __builtin_amdgcn_s_barrier(); \
                   asm volatile("" ::: "memory"); } while (0)
#define VMCNT(n) asm volatile("s_waitcnt vmcnt(" #n ")" ::: "memory")
#define LDF(p, imm) (*(const short8*)((p) + (imm)))

// ---- T19 region templates (masks: MFMA=0x8, VMEM=0x10, DS_READ=0x100) ----
__device__ __forceinline__ void sgb_x() {  // 16 MFMA, 4 DS, 2 VMEM
  __builtin_amdgcn_sched_group_barrier(0x010, 2, 0);
#pragma unroll
  for (int i = 0; i < 4; ++i) {
    __builtin_amdgcn_sched_group_barrier(0x008, 4, 0);
    __builtin_amdgcn_sched_group_barrier(0x100, 1, 0);
  }
}
__device__ __forceinline__ void sgb_y() {  // 16 MFMA, 0 DS, 2 VMEM
  __builtin_amdgcn_sched_group_barrier(0x010, 2, 0);
  __builtin_amdgcn_sched_group_barrier(0x008, 16, 0);
}
__device__ __forceinline__ void sgb_z() {  // 16 MFMA, 16 DS, 2 VMEM
  __builtin_amdgcn_sched_group_barrier(0x010, 2, 0);
#pragma unroll
  for (int i = 0; i < 8; ++i) {
    __builtin_amdgcn_sched_group_barrier(0x008, 2, 0);
    __builtin_amdgcn_sched_group_barrier(0x100, 2, 0);
  }
}

template <int M0>
__device__ __forceinline__ void mma_pair(f32x4 acc[8][4], const short8 a0[2],
                                         const short8 a1[2],
                                         const short8 bF[4][2]) {
  __builtin_amdgcn_s_setprio(1);
#pragma unroll
  for (int n = 0; n < 4; ++n)
#pragma unroll
    for (int s = 0; s < 2; ++s) {
      acc[M0][n] = __builtin_amdgcn_mfma_f32_16x16x32_bf16(a0[s], bF[n][s],
                                                           acc[M0][n], 0, 0, 0);
      acc[M0 + 1][n] = __builtin_amdgcn_mfma_f32_16x16x32_bf16(
          a1[s], bF[n][s], acc[M0 + 1][n], 0, 0, 0);
    }
  __builtin_amdgcn_s_setprio(0);
}

__global__ void __launch_bounds__(512, 2) gemm8(
    const ushort_t* __restrict__ abf, const ushort_t* __restrict__ wbf,
    const int* __restrict__ offs, float* __restrict__ out) {
  // [buf][mat 0=A/1=B][half][128 rows x 64 cols bf16] = 128 KiB
  __shared__ __align__(16) ushort_t lds[2][2][2][8192];

  // 2D XCD ownership: xcd owns tm band [8*xcd, 8*xcd+8); tn outer, tm inner.
  int bid = blockIdx.x;
  int loc = bid >> 3;                 // 0..175
  int tn = loc >> 3;                  // 0..21
  int tm = (bid & 7) * 8 + (loc & 7); // 0..63

  const int t = threadIdx.x;
  const int w = t >> 6;   // wave 0..7
  const int l = t & 63;
  const int wm = w >> 2;  // 0..1 : M-half of output
  const int wn = w & 3;   // 0..3 : N-quarter

  const int row0 = tm * 256;
  int e = 0;
#pragma unroll
  for (int i = 1; i < NEXP; ++i) e += (row0 >= offs[i]) ? 1 : 0;

  const ushort_t* aB = abf + (size_t)row0 * K_IN;
  const ushort_t* wB =
      wbf + (size_t)e * N_OUT * K_IN + (size_t)(tn * 256) * K_IN;
  const size_t H = (size_t)128 * K_IN;  // half-tile row offset in global

  // ---- hoisted stage source addressing (inverse-swizzled source cols) ----
  const size_t srow = (size_t)(2 * w) * 8 + (l >> 3);
  const int scol = ((l & 7) ^ (l >> 3)) * 8;
  const ushort_t* const sA0 = aB + srow * K_IN + scol;
  const ushort_t* const sA1 = aB + (srow + 8) * K_IN + scol;
  const ushort_t* const sW0 = wB + srow * K_IN + scol;
  const ushort_t* const sW1 = wB + (srow + 8) * K_IN + scol;

  auto stage2 = [&](const ushort_t* s0, const ushort_t* s1, ushort_t* lreg,
                    size_t ko) {
    __builtin_amdgcn_global_load_lds(
        (const __attribute__((address_space(1))) void*)(s0 + ko),
        (__attribute__((address_space(3))) void*)(lreg + (2 * w) * 512), 16, 0, 0);
    __builtin_amdgcn_global_load_lds(
        (const __attribute__((address_space(1))) void*)(s1 + ko),
        (__attribute__((address_space(3))) void*)(lreg + (2 * w + 1) * 512), 16, 0, 0);
  };

  f32x4 acc[8][4];
#pragma unroll
  for (int i = 0; i < 8; ++i)
#pragma unroll
    for (int j = 0; j < 4; ++j)
#pragma unroll
      for (int r = 0; r < 4; ++r) acc[i][j][r] = 0.f;

  // ---- hoisted fragment addressing ----
  const int l15 = l & 15;
  const int kgo2 = (l >> 4) * 16;
  const int swz = (l15 & 7) << 4;
  const int fo0 = l15 * 128 + (kgo2 ^ swz);
  const int fo1 = l15 * 128 + ((64 + kgo2) ^ swz);
  const char* aP[2][2];  // [buf][s]
  const char* bP[2][2];
#pragma unroll
  for (int b = 0; b < 2; ++b) {
    aP[b][0] = (const char*)&lds[b][0][wm][0] + fo0;
    aP[b][1] = (const char*)&lds[b][0][wm][0] + fo1;
    bP[b][0] = (const char*)&lds[b][1][wn >> 1][0] + (wn & 1) * 8192 + fo0;
    bP[b][1] = (const char*)&lds[b][1][wn >> 1][0] + (wn & 1) * 8192 + fo1;
  }

#define LDA_PAIR(d0, d1, buf, m)                          \
  do {                                                    \
    d0[0] = LDF(aP[buf][0], (m) * 2048);                  \
    d0[1] = LDF(aP[buf][1], (m) * 2048);                  \
    d1[0] = LDF(aP[buf][0], ((m) + 1) * 2048);            \
    d1[1] = LDF(aP[buf][1], ((m) + 1) * 2048);            \
  } while (0)
#define LDB_ALL(dst, buf)                                 \
  do {                                                    \
    _Pragma("unroll")                                     \
    for (int n = 0; n < 4; ++n) {                         \
      dst[n][0] = LDF(bP[buf][0], n * 2048);              \
      dst[n][1] = LDF(bP[buf][1], n * 2048);              \
    }                                                     \
  } while (0)

  // ---- prologue: tile0 -> b0; tile1.B + tile1.A0 -> b1 (14 loads/wave) ----
  stage2(sA0, sA1, &lds[0][0][0][0], 0);
  stage2(sA0, sA1, &lds[0][0][1][0], H);
  stage2(sW0, sW1, &lds[0][1][0][0], 0);
  stage2(sW0, sW1, &lds[0][1][1][0], H);
  stage2(sW0, sW1, &lds[1][1][0][0], 64);
  stage2(sW0, sW1, &lds[1][1][1][0], H + 64);
  stage2(sA0, sA1, &lds[1][0][0][0], 64);  // b1.A0 @ kO1(J=0)
  VMCNT(6);  // retire tile0's 8 loads; 6 (tile1.B + tile1.A0) in flight
  BAR();

  short8 bF[4][2];
  short8 r0a[2], r0b[2];
  short8 r1a[2], r1b[2];
  LDB_ALL(bF, 0);
  LDA_PAIR(r0a, r0b, 0, 0);
  LDA_PAIR(r1a, r1b, 0, 2);

  // ---- steady loop: 15 iterations, straight-line regions ----
#pragma unroll 1
  for (int J = 0; J < 15; ++J) {
    const size_t kO1 = (size_t)(2 * J + 1) * 64;
    const size_t kO2 = (size_t)(2 * J + 2) * 64;
    const size_t kO3 = (size_t)(2 * J + 3) * 64;

    // R1: mma m0-1(b0,R0); stage b1.A1; prefetch R0<-b0.A45
    sgb_x();
    mma_pair<0>(acc, r0a, r0b, bF);
    stage2(sA0, sA1, &lds[1][0][1][0], H + kO1);
    LDA_PAIR(r0a, r0b, 0, 4);
    BAR();
    // R2: mma m2-3(R1); stage b0.B0'; prefetch R1<-b0.A67
    sgb_x();
    mma_pair<2>(acc, r1a, r1b, bF);
    stage2(sW0, sW1, &lds[0][1][0][0], kO2);
    LDA_PAIR(r1a, r1b, 0, 6);
    BAR();
    // R3: mma m4-5(R0); stage b0.B1'; VMCNT(4) -> buf1 landed
    sgb_y();
    mma_pair<4>(acc, r0a, r0b, bF);
    stage2(sW0, sW1, &lds[0][1][1][0], H + kO2);
    VMCNT(4);
    BAR();
    // R4: mma m6-7(R1); LDB<-b1; R0<-b1.A01; stage b0.A0'; R1<-b1.A23
    sgb_z();
    mma_pair<6>(acc, r1a, r1b, bF);
    LDB_ALL(bF, 1);
    LDA_PAIR(r0a, r0b, 1, 0);
    stage2(sA0, sA1, &lds[0][0][0][0], kO2);
    LDA_PAIR(r1a, r1b, 1, 2);
    BAR();
    // R5: mma m0-1(b1,R0); stage b0.A1'; prefetch R0<-b1.A45
    sgb_x();
    mma_pair<0>(acc, r0a, r0b, bF);
    stage2(sA0, sA1, &lds[0][0][1][0], H + kO2);
    LDA_PAIR(r0a, r0b, 1, 4);
    BAR();
    // R6: mma m2-3(R1); stage b1.B0''; prefetch R1<-b1.A67
    sgb_x();
    mma_pair<2>(acc, r1a, r1b, bF);
    stage2(sW0, sW1, &lds[1][1][0][0], kO3);
    LDA_PAIR(r1a, r1b, 1, 6);
    BAR();
    // R7: mma m4-5(R0); stage b1.B1''; VMCNT(4) -> buf0' landed
    sgb_y();
    mma_pair<4>(acc, r0a, r0b, bF);
    stage2(sW0, sW1, &lds[1][1][1][0], H + kO3);
    VMCNT(4);
    BAR();
    // R8: mma m6-7(R1); LDB<-b0'; R0<-b0'.A01; stage b1.A0''; R1<-b0'.A23
    sgb_z();
    mma_pair<6>(acc, r1a, r1b, bF);
    LDB_ALL(bF, 0);
    LDA_PAIR(r0a, r0b, 0, 0);
    stage2(sA0, sA1, &lds[1][0][0][0], kO3);  // = kO1 of J+1
    LDA_PAIR(r1a, r1b, 0, 2);
    BAR();
  }

  // ---- peeled tail: J=15 (kO1 = 31*64 = 1984) ----
  {
    sgb_x();
    mma_pair<0>(acc, r0a, r0b, bF);
    stage2(sA0, sA1, &lds[1][0][1][0], H + 1984);  // b1.A1 (last half-tile)
    LDA_PAIR(r0a, r0b, 0, 4);
    BAR();
    sgb_x();
    mma_pair<2>(acc, r1a, r1b, bF);
    LDA_PAIR(r1a, r1b, 0, 6);
    BAR();
    sgb_y();
    mma_pair<4>(acc, r0a, r0b, bF);
    VMCNT(0);  // drain: buf1 fully landed
    BAR();
    sgb_z();
    mma_pair<6>(acc, r1a, r1b, bF);
    LDB_ALL(bF, 1);
    LDA_PAIR(r0a, r0b, 1, 0);
    LDA_PAIR(r1a, r1b, 1, 2);
    BAR();
    sgb_x();
    mma_pair<0>(acc, r0a, r0b, bF);
    LDA_PAIR(r0a, r0b, 1, 4);
    BAR();
    sgb_x();
    mma_pair<2>(acc, r1a, r1b, bF);
    LDA_PAIR(r1a, r1b, 1, 6);
    BAR();
    sgb_y();
    mma_pair<4>(acc, r0a, r0b, bF);
    BAR();
    mma_pair<6>(acc, r1a, r1b, bF);
  }

  // ---- epilogue: C/D layout col=lane&15, row=(lane>>4)*4+reg ----
  const int cr = (l >> 4) * 4;
  const int cc = l & 15;
  float* ob = out + (size_t)(row0 + wm * 128) * N_OUT + tn * 256 + wn * 64;
#pragma unroll
  for (int m = 0; m < 8; ++m)
#pragma unroll
    for (int n = 0; n < 4; ++n)
#pragma unroll
      for (int r = 0; r < 4; ++r)
        ob[(size_t)(m * 16 + cr + r) * N_OUT + n * 16 + cc] = acc[m][n][r];
#undef LDA_PAIR
#undef LDB_ALL
}

// ---------------- fallback (ws too small): fp32 reg-staging 128x128 ----------------
#define BM 128
#define BN 128
#define BK 64
#define MT (T_TOK / BM)
#define NTILE (N_OUT / BN)

__global__ void __launch_bounds__(256) gemm_fb(const float* __restrict__ af,
                                               const float* __restrict__ wf,
                                               const int* __restrict__ offs,
                                               float* __restrict__ out) {
  __shared__ __align__(16) ushort_t lsA[BM * BK];
  __shared__ __align__(16) ushort_t lsB[BN * BK];
  int bid = blockIdx.x;
  int wg = (bid & 7) * ((MT * NTILE) >> 3) + (bid >> 3);
  int tm = wg / NTILE, tn = wg - tm * NTILE;
  const int t = threadIdx.x, w = t >> 6, l = t & 63;
  const int row0 = tm * BM;
  int e = 0;
#pragma unroll
  for (int i = 1; i < NEXP; ++i) e += (row0 >= offs[i]) ? 1 : 0;
  const size_t wbase = (size_t)e * ((size_t)N_OUT * K_IN);
  f32x4 acc[4][4];
#pragma unroll
  for (int i = 0; i < 4; ++i)
#pragma unroll
    for (int j = 0; j < 4; ++j)
#pragma unroll
      for (int r = 0; r < 4; ++r) acc[i][j][r] = 0.f;
  const int wm = w >> 1, wn = w & 1;
  const int rA = wm * 64 + (l & 15), rB = wn * 64 + (l & 15);
  const int kgo = (l >> 4) * 8;
  for (int kt = 0; kt < K_IN / BK; ++kt) {
    const int k0 = kt * BK;
    if (kt) __syncthreads();
#pragma unroll
    for (int p = 0; p < 4; ++p) {
      const int ia = (p * 4 + w) * 64 + l;
      const float4* g = (const float4*)(af + (size_t)(row0 + (ia >> 3)) * K_IN +
                                        k0 + (ia & 7) * 8);
      float4 a = g[0], b = g[1];
      short8 v;
      v[0] = (short)f2bf(a.x); v[1] = (short)f2bf(a.y);
      v[2] = (short)f2bf(a.z); v[3] = (short)f2bf(a.w);
      v[4] = (short)f2bf(b.x); v[5] = (short)f2bf(b.y);
      v[6] = (short)f2bf(b.z); v[7] = (short)f2bf(b.w);
      *(short8*)&lsA[ia * 8] = v;
    }
#pragma unroll
    for (int p = 0; p < 4; ++p) {
      const int ib = (p * 4 + w) * 64 + l;
      const float4* g = (const float4*)(wf + wbase +
                                        (size_t)(tn * BN + (ib >> 3)) * K_IN +
                                        k0 + (ib & 7) * 8);
      float4 a = g[0], b = g[1];
      short8 v;
      v[0] = (short)f2bf(a.x); v[1] = (short)f2bf(a.y);
      v[2] = (short)f2bf(a.z); v[3] = (short)f2bf(a.w);
      v[4] = (short)f2bf(b.x); v[5] = (short)f2bf(b.y);
      v[6] = (short)f2bf(b.z); v[7] = (short)f2bf(b.w);
      *(short8*)&lsB[ib * 8] = v;
    }
    __syncthreads();
#pragma unroll
    for (int s = 0; s < 2; ++s) {
      const int ko = s * 32 + kgo;
      short8 aF[4], bFf[4];
#pragma unroll
      for (int i = 0; i < 4; ++i) aF[i] = *(const short8*)&lsA[(rA + i * 16) * BK + ko];
#pragma unroll
      for (int j = 0; j < 4; ++j) bFf[j] = *(const short8*)&lsB[(rB + j * 16) * BK + ko];
#pragma unroll
      for (int i = 0; i < 4; ++i)
#pragma unroll
        for (int j = 0; j < 4; ++j)
          acc[i][j] = __builtin_amdgcn_mfma_f32_16x16x32_bf16(aF[i], bFf[j],
                                                              acc[i][j], 0, 0, 0);
    }
  }
  const int cr = (l >> 4) * 4, cc = l & 15;
  float* ob = out + (size_t)(row0 + wm * 64) * N_OUT + tn * BN + wn * 64;
#pragma unroll
  for (int i = 0; i < 4; ++i)
#pragma unroll
    for (int j = 0; j < 4; ++j)
#pragma unroll
      for (int r = 0; r < 4; ++r)
        ob[(size_t)(i * 16 + cr + r) * N_OUT + j * 16 + cc] = acc[i][j][r];
}

extern "C" void kernel_launch(void* const* d_in, const int* in_sizes, int n_in,
                              void* d_out, int out_size, void* d_ws, size_t ws_size,
                              hipStream_t stream) {
  const float* x = (const float*)d_in[0];
  const float* wt = (const float*)d_in[1];
  const int* offs = (const int*)d_in[2];
  float* out = (float*)d_out;

  const size_t nA = (size_t)T_TOK * K_IN;
  const size_t nW = (size_t)NEXP * N_OUT * K_IN;
  const size_t need = (nA + nW) * sizeof(ushort_t);

  if (ws_size >= need) {
    ushort_t* abf = (ushort_t*)d_ws;
    ushort_t* wbf = abf + nA;
    cvt2<<<2048, 256, 0, stream>>>(x, wt, abf, wbf, (int)(nA / 8),
                                   (int)((nA + nW) / 8));
    gemm8<<<GRID2, 512, 0, stream>>>(abf, wbf, offs, out);
  } else {
    gemm_fb<<<MT * NTILE, 256, 0, stream>>>(x, wt, offs, out);
  }
}